// Round 3
// baseline (225.927 us; speedup 1.0000x reference)
//
#include <hip/hip_runtime.h>
#include <math.h>

#define NPTS 4096
#define NSMP 10

// ---------------- prep: fuse (w1,b1,w2,b2) -> Wn[30][64] (layout [s*3+c][p]), bb[64] ----
// out[p] = bb[p] + sum_{s,c} Wn[s*3+c][p] * pos[b,c,idx_s]
// Valid because the MLP has no nonlinearity between the two layers.
__global__ void prep_kernel(const float* __restrict__ w1, const float* __restrict__ b1,
                            const float* __restrict__ w2, const float* __restrict__ b2,
                            float* __restrict__ wn, float* __restrict__ bb) {
  const int p = threadIdx.x;
  if (p >= 64) return;
  // slot index for (g,p,q): s = INDS[(2i+di_g)*4 + (2j+dj_g)], groups a,d,b,c
  const int sg[16] = {0,2,4,6, 3,5,7,9, 1,3,5,7, 2,4,6,8};
  float wloc[30];
  #pragma unroll
  for (int i = 0; i < 30; ++i) wloc[i] = 0.0f;
  #pragma unroll
  for (int g = 0; g < 4; ++g)
    #pragma unroll
    for (int i = 0; i < 2; ++i)
      #pragma unroll
      for (int j = 0; j < 2; ++j) {
        const int s = sg[g*4 + i*2 + j];
        #pragma unroll
        for (int c = 0; c < 3; ++c) {
          const int k = (c + 3*g)*4 + i*2 + j;   // w1 flat index over (12,2,2)
          float wk = 0.0f;
          for (int o = 0; o < 64; ++o) wk = fmaf(w2[p*64 + o], w1[o*48 + k], wk);
          wloc[s*3 + c] += wk;
        }
      }
  for (int i = 0; i < 30; ++i) wn[i*64 + p] = wloc[i];
  float sb = 0.0f;
  for (int o = 0; o < 64; ++o) sb = fmaf(w2[p*64 + o], b1[o], sb);
  bb[p] = b2[p] + sb;
}

// ---------------- topk: exact 10-NN per row, f64-ranked, reference-order indices ----
// One wave per row n. Lane L owns candidates m = k*64+L (k=0..63), caches f32 d2 in regs.
// tau = 10th-smallest of the 64 lane-minima (safe bound on the row's 10th distance).
// Collect d2 <= tau(+slack) (~20 entries) into LDS, then RE-RANK the survivors with
// FLOAT64 d2 (expanded formula) and bitonic-sort (d2_64, idx) lexicographic.
// Rationale: selection order must match the harness's numpy float64 reference; f64
// op-order deltas (~1e-15) are far below rank-boundary gaps (~5e-3), so any
// consistent f64 evaluation yields the reference ordering. The f32 prefilter is
// superset-safe: |d2_f32 - d2_f64| <= ~2e-5 (cancellation at |sq| <= ~60), slack 1e-4.
__global__ __launch_bounds__(256, 2) void topk_kernel(const float* __restrict__ pos,
                                                      int* __restrict__ idx_out) {
  __shared__ float4 pts[NPTS];      // (x, y, z, sq_f32) per point: 64 KB
  __shared__ int   cnt[4];
  __shared__ int   bufi[4][64];

  const int b    = blockIdx.y;
  const int tid  = threadIdx.x;
  const int lane = tid & 63;
  const int wv   = tid >> 6;
  const float* pb = pos + (size_t)b * 3 * NPTS;

  for (int i = tid; i < NPTS; i += 256) {
    float x = pb[i], y = pb[i + NPTS], z = pb[i + 2 * NPTS];
    float sq = __fadd_rn(__fadd_rn(__fmul_rn(x, x), __fmul_rn(y, y)), __fmul_rn(z, z));
    pts[i] = make_float4(x, y, z, sq);
  }
  __syncthreads();

  const int rowbase = blockIdx.x * 64;
  #pragma unroll 1
  for (int rr = 0; rr < 16; ++rr) {
    const int n = rowbase + wv * 16 + rr;
    const float4 q = pts[n];              // wave-uniform broadcast read

    // ---- pass 1 (f32): d2 for 64 strided candidates, cached; track lane min ----
    float dc[64];
    float dmin = INFINITY;
    #pragma unroll
    for (int k = 0; k < 64; ++k) {
      float4 p = pts[k * 64 + lane];
      float dot = __fmaf_rn(q.z, p.z, __fmaf_rn(q.y, p.y, __fmul_rn(q.x, p.x)));
      float d2 = __fadd_rn(__fsub_rn(q.w, __fmul_rn(2.0f, dot)), p.w);
      dc[k] = d2;
      dmin = fminf(dmin, d2);
    }

    // ---- tau = 10th smallest of the 64 lane minima (bitonic, values only) ----
    float v = dmin;
    #pragma unroll
    for (int k2 = 2; k2 <= 64; k2 <<= 1) {
      #pragma unroll
      for (int j = k2 >> 1; j > 0; j >>= 1) {
        float o = __shfl_xor(v, j);
        bool keepMin = (((lane & k2) == 0) == ((lane & j) == 0));
        v = keepMin ? fminf(v, o) : fmaxf(v, o);
      }
    }
    float tau = __shfl(v, 9);
    // inflate so the f32 filter provably keeps every f64-top-10 candidate
    float tauX = __fadd_rn(__fadd_rn(tau, 1e-4f), __fmul_rn(fabsf(tau), 1e-5f));

    // ---- pass 2: collect candidate indices with d2_f32 <= tauX ----
    if (lane == 0) cnt[wv] = 0;           // same-wave DS ops are in-order
    #pragma unroll
    for (int k = 0; k < 64; ++k) {
      if (dc[k] <= tauX) {
        int p = atomicAdd(&cnt[wv], 1);
        if (p < 64) bufi[wv][p] = k * 64 + lane;
      }
    }
    int c = cnt[wv];
    if (c > 64) c = 64;

    // ---- pass 3 (f64): exact re-rank of survivors ----
    double sd; int si;
    if (lane < c) {
      si = bufi[wv][lane];
      float4 p = pts[si];
      double qx = (double)q.x, qy = (double)q.y, qz = (double)q.z;
      double px = (double)p.x, py = (double)p.y, pz = (double)p.z;
      double dot = qx * px + qy * py + qz * pz;      // products exact from f32 inputs
      double sqn = qx * qx + qy * qy + qz * qz;
      double sqm = px * px + py * py + pz * pz;
      sd = (sqn - 2.0 * dot) + sqm;                  // self -> exactly 0.0
    } else {
      sd = (double)INFINITY; si = 0x7FFFFFFF;
    }
    #pragma unroll
    for (int k2 = 2; k2 <= 64; k2 <<= 1) {
      #pragma unroll
      for (int j = k2 >> 1; j > 0; j >>= 1) {
        double od = __shfl_xor(sd, j);
        int    oi = __shfl_xor(si, j);
        bool keepMin = (((lane & k2) == 0) == ((lane & j) == 0));
        bool otherSmaller = (od < sd) || (od == sd && oi < si);
        bool take = keepMin ? otherSmaller : !otherSmaller;
        if (take) { sd = od; si = oi; }
      }
    }
    if (lane < NSMP)
      idx_out[((size_t)b * NPTS + n) * NSMP + lane] = si;
  }
}

// ---------------- mlp: out[b,p,n] = bb[p] + sum_{s,c} Wn[s*3+c][p]*pos[b,c,idx_s] ----
__global__ __launch_bounds__(256) void mlp_kernel(const float* __restrict__ pos,
                                                  const int* __restrict__ nbr,
                                                  const float* __restrict__ wn,
                                                  const float* __restrict__ bbg,
                                                  float* __restrict__ out) {
  __shared__ __align__(16) float wl[30 * 64];
  __shared__ float bl[64];
  const int b = blockIdx.y;
  const int tid = threadIdx.x;
  for (int i = tid; i < 30 * 64; i += 256) wl[i] = wn[i];
  if (tid < 64) bl[tid] = bbg[tid];
  __syncthreads();

  const int n = blockIdx.x * 256 + tid;
  const float* pb = pos + (size_t)b * 3 * NPTS;
  const int* ip = nbr + ((size_t)b * NPTS + n) * NSMP;

  float pxyz[30];
  #pragma unroll
  for (int s = 0; s < NSMP; ++s) {
    int i = ip[s];
    pxyz[s * 3 + 0] = pb[i];
    pxyz[s * 3 + 1] = pb[i + NPTS];
    pxyz[s * 3 + 2] = pb[i + 2 * NPTS];
  }

  float acc[64];
  #pragma unroll
  for (int p = 0; p < 64; ++p) acc[p] = bl[p];
  #pragma unroll
  for (int sc = 0; sc < 30; ++sc) {
    float vv = pxyz[sc];
    const float4* w4 = (const float4*)(&wl[sc * 64]);   // wave-uniform broadcast b128
    #pragma unroll
    for (int pq = 0; pq < 16; ++pq) {
      float4 w = w4[pq];
      acc[pq * 4 + 0] = fmaf(w.x, vv, acc[pq * 4 + 0]);
      acc[pq * 4 + 1] = fmaf(w.y, vv, acc[pq * 4 + 1]);
      acc[pq * 4 + 2] = fmaf(w.z, vv, acc[pq * 4 + 2]);
      acc[pq * 4 + 3] = fmaf(w.w, vv, acc[pq * 4 + 3]);
    }
  }

  float* ob = out + ((size_t)b * 64) * NPTS + n;        // out layout (B,64,N)
  #pragma unroll
  for (int p = 0; p < 64; ++p) ob[p * NPTS] = acc[p];   // coalesced across lanes
}

extern "C" void kernel_launch(void* const* d_in, const int* in_sizes, int n_in,
                              void* d_out, int out_size, void* d_ws, size_t ws_size,
                              hipStream_t stream) {
  (void)in_sizes; (void)n_in; (void)out_size; (void)ws_size;
  const float* pos = (const float*)d_in[0];
  const float* w1  = (const float*)d_in[1];
  const float* b1  = (const float*)d_in[2];
  const float* w2  = (const float*)d_in[3];
  const float* b2  = (const float*)d_in[4];
  float* out = (float*)d_out;

  // workspace layout: [0, 1310720) idx (8*4096*10 int); then Wn (30*64 f32); then bb (64 f32)
  int*   nbr = (int*)d_ws;
  float* wn  = (float*)((char*)d_ws + 1310720);
  float* bb  = (float*)((char*)d_ws + 1310720 + 30 * 64 * 4);

  prep_kernel<<<dim3(1), dim3(64), 0, stream>>>(w1, b1, w2, b2, wn, bb);
  topk_kernel<<<dim3(64, 8), dim3(256), 0, stream>>>(pos, nbr);
  mlp_kernel<<<dim3(16, 8), dim3(256), 0, stream>>>(pos, nbr, wn, bb, out);
}

// Round 4
// 188.455 us; speedup vs baseline: 1.1988x; 1.1988x over previous
//
#include <hip/hip_runtime.h>
#include <math.h>

#define NPTS 4096
#define NSMP 10

typedef float f32x2 __attribute__((ext_vector_type(2)));

// ---------------- prep: fuse (w1,b1,w2,b2) -> Wn[30][64] (layout [s*3+c][p]), bb[64] ----
// out[p] = bb[p] + sum_{s,c} Wn[s*3+c][p] * pos[b,c,idx_s]  (no nonlinearity -> legal fuse)
// 256 threads: (p = t&63, grp = t>>6) each sums a 16-wide o-chunk, LDS-reduced.
__global__ void prep_kernel(const float* __restrict__ w1, const float* __restrict__ b1,
                            const float* __restrict__ w2, const float* __restrict__ b2,
                            float* __restrict__ wn, float* __restrict__ bb) {
  __shared__ float part[4][30][64];   // 30 KB
  __shared__ float bpart[4][64];
  const int t = threadIdx.x, p = t & 63, grp = t >> 6, o0 = grp * 16;
  const int sg[16] = {0,2,4,6, 3,5,7,9, 1,3,5,7, 2,4,6,8};
  float w2r[16];
  #pragma unroll
  for (int oo = 0; oo < 16; ++oo) w2r[oo] = w2[p * 64 + o0 + oo];
  float wloc[30];
  #pragma unroll
  for (int i = 0; i < 30; ++i) wloc[i] = 0.0f;
  #pragma unroll
  for (int g = 0; g < 4; ++g)
    #pragma unroll
    for (int i = 0; i < 2; ++i)
      #pragma unroll
      for (int j = 0; j < 2; ++j) {
        const int s = sg[g * 4 + i * 2 + j];
        #pragma unroll
        for (int c = 0; c < 3; ++c) {
          const int k = (c + 3 * g) * 4 + i * 2 + j;   // w1 flat index over (12,2,2)
          float wk = 0.0f;
          #pragma unroll
          for (int oo = 0; oo < 16; ++oo)
            wk = fmaf(w2r[oo], w1[(o0 + oo) * 48 + k], wk);
          wloc[s * 3 + c] += wk;
        }
      }
  #pragma unroll
  for (int i = 0; i < 30; ++i) part[grp][i][p] = wloc[i];
  float sb = 0.0f;
  #pragma unroll
  for (int oo = 0; oo < 16; ++oo) sb = fmaf(w2r[oo], b1[o0 + oo], sb);
  bpart[grp][p] = sb;
  __syncthreads();
  const float* p0 = &part[0][0][0];
  for (int idx = t; idx < 30 * 64; idx += 256)
    wn[idx] = p0[idx] + p0[1920 + idx] + p0[3840 + idx] + p0[5760 + idx];
  if (t < 64) bb[t] = b2[t] + bpart[0][t] + bpart[1][t] + bpart[2][t] + bpart[3][t];
}

// ---------------- topk: exact 10-NN per row (f64-ranked), R=8 rows per wave batch ----
// Lane L owns candidates m = k*64+L. Key = sqm - 2*dot (row-const sqn dropped; order-
// preserving). Pass 1: one ds_read_b128 serves 8 rows (pair-packed f32x2 math); track
// per-row lane-min. Tau per row: ballot-bisection (no DS) for an upper bound on the
// 10th-smallest lane-min (>= row's 10th-smallest key). Pass 2: recompute keys, push
// survivors (key <= tau + slack, ~10-30) to per-wave/per-row LDS buffers. Pass 3:
// f64 re-rank (expanded formula, matches np-f64 reference ordering; self -> exact 0)
// via readlane rank-count, lex (d2,idx) tiebreak. Slack 2e-4 >> 2*|f32-f64| (~4e-5),
// so the f64-top-10 provably survives the f32 prefilter.
__global__ __launch_bounds__(256, 2) void topk_kernel(const float* __restrict__ pos,
                                                      int* __restrict__ idx_out) {
  __shared__ float4 pts[NPTS];        // (x,y,z,sq_f32): 64 KB
  __shared__ int cnt[4][8];
  __shared__ int bufi[4][8][64];      // 8 KB

  const int b = blockIdx.y, tid = threadIdx.x, lane = tid & 63, wv = tid >> 6;
  const float* pb = pos + (size_t)b * 3 * NPTS;
  for (int i = tid; i < NPTS; i += 256) {
    float x = pb[i], y = pb[i + NPTS], z = pb[i + 2 * NPTS];
    float sq = __fadd_rn(__fadd_rn(__fmul_rn(x, x), __fmul_rn(y, y)), __fmul_rn(z, z));
    pts[i] = make_float4(x, y, z, sq);
  }
  __syncthreads();

  const int rowbase = blockIdx.x * 64 + wv * 16;
  #pragma unroll 1
  for (int bt = 0; bt < 2; ++bt) {
    const int n0 = rowbase + bt * 8;

    // load 8 queries, pair-packed (wave-uniform broadcast reads)
    f32x2 qx[4], qy[4], qz[4], dmin[4];
    #pragma unroll
    for (int pp = 0; pp < 4; ++pp) {
      float4 qa = pts[n0 + 2 * pp], qb = pts[n0 + 2 * pp + 1];
      qx[pp].x = qa.x; qx[pp].y = qb.x;
      qy[pp].x = qa.y; qy[pp].y = qb.y;
      qz[pp].x = qa.z; qz[pp].y = qb.z;
      dmin[pp].x = INFINITY; dmin[pp].y = INFINITY;
    }

    // ---- pass 1: per-row lane minima (1 LDS read per candidate serves 8 rows) ----
    #pragma unroll 8
    for (int k = 0; k < 64; ++k) {
      float4 p = pts[k * 64 + lane];
      #pragma unroll
      for (int pp = 0; pp < 4; ++pp) {
        f32x2 dot = qx[pp] * p.x + qy[pp] * p.y + qz[pp] * p.z;
        f32x2 key = (-2.0f) * dot + p.w;
        dmin[pp] = __builtin_elementwise_min(dmin[pp], key);
      }
    }

    // ---- tau per row: ballot bisection on monotone-u32 (DS-free) ----
    float tx[8];
    #pragma unroll
    for (int r = 0; r < 8; ++r) {
      float dm = (r & 1) ? dmin[r >> 1].y : dmin[r >> 1].x;
      unsigned ub = __float_as_uint(dm);
      unsigned um = (ub & 0x80000000u) ? ~ub : (ub | 0x80000000u);
      unsigned lo = 0u, hi = 0xFFFFFFFFu;
      #pragma unroll 1
      for (int it = 0; it < 24; ++it) {
        unsigned mid = lo + ((hi - lo) >> 1);
        int c10 = __popcll(__ballot(um <= mid));   // invariant: count(<=hi) >= 10
        if (c10 >= NSMP) hi = mid; else lo = mid + 1;
      }
      unsigned tb = (hi & 0x80000000u) ? (hi ^ 0x80000000u) : ~hi;
      float tf = __uint_as_float(tb);
      tx[r] = __fadd_rn(__fadd_rn(tf, 2e-4f), __fmul_rn(fabsf(tf), 1e-5f));
    }

    if (lane < 8) cnt[wv][lane] = 0;   // same-wave DS ops are in-order

    // ---- pass 2: recompute keys, push survivors per row ----
    #pragma unroll 2
    for (int k = 0; k < 64; ++k) {
      float4 p = pts[k * 64 + lane];
      #pragma unroll
      for (int pp = 0; pp < 4; ++pp) {
        f32x2 dot = qx[pp] * p.x + qy[pp] * p.y + qz[pp] * p.z;
        f32x2 key = (-2.0f) * dot + p.w;
        if (key.x <= tx[2 * pp]) {
          int ps = atomicAdd(&cnt[wv][2 * pp], 1);
          if (ps < 64) bufi[wv][2 * pp][ps] = k * 64 + lane;
        }
        if (key.y <= tx[2 * pp + 1]) {
          int ps = atomicAdd(&cnt[wv][2 * pp + 1], 1);
          if (ps < 64) bufi[wv][2 * pp + 1][ps] = k * 64 + lane;
        }
      }
    }

    // ---- pass 3: f64 re-rank via readlane rank-count; rank = output slot ----
    #pragma unroll 1
    for (int r = 0; r < 8; ++r) {
      int c = __builtin_amdgcn_readfirstlane(cnt[wv][r]);
      if (c > 64) c = 64;
      float qxr = (r & 1) ? qx[r >> 1].y : qx[r >> 1].x;
      float qyr = (r & 1) ? qy[r >> 1].y : qy[r >> 1].x;
      float qzr = (r & 1) ? qz[r >> 1].y : qz[r >> 1].x;
      double d; int si;
      if (lane < c) {
        si = bufi[wv][r][lane];
        float4 p = pts[si];
        double dqx = (double)qxr, dqy = (double)qyr, dqz = (double)qzr;
        double px = (double)p.x, py = (double)p.y, pz = (double)p.z;
        double dot = dqx * px + dqy * py + dqz * pz;
        double sqn = dqx * dqx + dqy * dqy + dqz * dqz;
        double sqm = px * px + py * py + pz * pz;
        d = (sqn - 2.0 * dot) + sqm;               // self -> exactly 0.0
      } else { d = (double)INFINITY; si = 0x7FFFFFFF; }
      int dlo = __double2loint(d), dhi = __double2hiint(d);
      int rank = 0;
      #pragma unroll 1
      for (int j = 0; j < c; ++j) {
        int jlo = __builtin_amdgcn_readlane(dlo, j);
        int jhi = __builtin_amdgcn_readlane(dhi, j);
        int ji  = __builtin_amdgcn_readlane(si, j);
        double jd = __hiloint2double(jhi, jlo);
        if (jd < d || (jd == d && ji < si)) ++rank;
      }
      if (lane < c && rank < NSMP)
        idx_out[((size_t)b * NPTS + n0 + r) * NSMP + rank] = si;
    }
  }
}

// ---------------- mlp: out[b,p,n] = bb[p] + sum_{s,c} Wn[s*3+c][p]*pos[b,c,idx_s] ----
__global__ __launch_bounds__(256) void mlp_kernel(const float* __restrict__ pos,
                                                  const int* __restrict__ nbr,
                                                  const float* __restrict__ wn,
                                                  const float* __restrict__ bbg,
                                                  float* __restrict__ out) {
  __shared__ __align__(16) float wl[30 * 64];
  __shared__ float bl[64];
  const int b = blockIdx.y;
  const int tid = threadIdx.x;
  for (int i = tid; i < 30 * 64; i += 256) wl[i] = wn[i];
  if (tid < 64) bl[tid] = bbg[tid];
  __syncthreads();

  const int n = blockIdx.x * 256 + tid;
  const float* pb = pos + (size_t)b * 3 * NPTS;
  const int* ip = nbr + ((size_t)b * NPTS + n) * NSMP;

  float pxyz[30];
  #pragma unroll
  for (int s = 0; s < NSMP; ++s) {
    int i = ip[s];
    pxyz[s * 3 + 0] = pb[i];
    pxyz[s * 3 + 1] = pb[i + NPTS];
    pxyz[s * 3 + 2] = pb[i + 2 * NPTS];
  }

  float acc[64];
  #pragma unroll
  for (int p = 0; p < 64; ++p) acc[p] = bl[p];
  #pragma unroll
  for (int sc = 0; sc < 30; ++sc) {
    float vv = pxyz[sc];
    const float4* w4 = (const float4*)(&wl[sc * 64]);   // wave-uniform broadcast b128
    #pragma unroll
    for (int pq = 0; pq < 16; ++pq) {
      float4 w = w4[pq];
      acc[pq * 4 + 0] = fmaf(w.x, vv, acc[pq * 4 + 0]);
      acc[pq * 4 + 1] = fmaf(w.y, vv, acc[pq * 4 + 1]);
      acc[pq * 4 + 2] = fmaf(w.z, vv, acc[pq * 4 + 2]);
      acc[pq * 4 + 3] = fmaf(w.w, vv, acc[pq * 4 + 3]);
    }
  }

  float* ob = out + ((size_t)b * 64) * NPTS + n;        // out layout (B,64,N)
  #pragma unroll
  for (int p = 0; p < 64; ++p) ob[p * NPTS] = acc[p];   // coalesced across lanes
}

extern "C" void kernel_launch(void* const* d_in, const int* in_sizes, int n_in,
                              void* d_out, int out_size, void* d_ws, size_t ws_size,
                              hipStream_t stream) {
  (void)in_sizes; (void)n_in; (void)out_size; (void)ws_size;
  const float* pos = (const float*)d_in[0];
  const float* w1  = (const float*)d_in[1];
  const float* b1  = (const float*)d_in[2];
  const float* w2  = (const float*)d_in[3];
  const float* b2  = (const float*)d_in[4];
  float* out = (float*)d_out;

  // workspace layout: [0, 1310720) idx (8*4096*10 int); then Wn (30*64 f32); then bb (64 f32)
  int*   nbr = (int*)d_ws;
  float* wn  = (float*)((char*)d_ws + 1310720);
  float* bb  = (float*)((char*)d_ws + 1310720 + 30 * 64 * 4);

  prep_kernel<<<dim3(1), dim3(256), 0, stream>>>(w1, b1, w2, b2, wn, bb);
  topk_kernel<<<dim3(64, 8), dim3(256), 0, stream>>>(pos, nbr);
  mlp_kernel<<<dim3(16, 8), dim3(256), 0, stream>>>(pos, nbr, wn, bb, out);
}

// Round 5
// 150.274 us; speedup vs baseline: 1.5034x; 1.2541x over previous
//
#include <hip/hip_runtime.h>
#include <math.h>

#define NPTS 4096
#define NSMP 10

typedef float f32x2 __attribute__((ext_vector_type(2)));

// ---------------- prep: fuse (w1,b1,w2,b2) -> Wn[30][64] ([s*3+c][p]), bb[64] ----------
// out[p] = bb[p] + sum_{s,c} Wn[s*3+c][p] * pos[b,c,idx_s]  (no nonlinearity -> legal).
// All of w1/w2/b1 staged in LDS first (coalesced): R3/R4 read w1 via ~768 uniform GLOBAL
// loads per thread from a single block -> ~200cyc L2 latency each, serial. LDS fixes it.
__global__ __launch_bounds__(256) void prep_kernel(
    const float* __restrict__ w1, const float* __restrict__ b1,
    const float* __restrict__ w2, const float* __restrict__ b2,
    float* __restrict__ wn, float* __restrict__ bb) {
  __shared__ float w1l[64 * 48];      // 12 KB, [o][k]
  __shared__ float w2t[64 * 64];      // 16 KB, transposed [o][p] (lane reads stride-1)
  __shared__ float b1l[64];
  __shared__ float part[4][30][64];   // 30 KB
  __shared__ float bpart[4][64];
  const int t = threadIdx.x, p = t & 63, grp = t >> 6, o0 = grp * 16;
  for (int idx = t; idx < 64 * 48; idx += 256) w1l[idx] = w1[idx];
  for (int idx = t; idx < 64 * 64; idx += 256) w2t[(idx & 63) * 64 + (idx >> 6)] = w2[idx];
  if (t < 64) b1l[t] = b1[t];
  __syncthreads();

  const int sg[16] = {0,2,4,6, 3,5,7,9, 1,3,5,7, 2,4,6,8};
  float w2r[16];
  #pragma unroll
  for (int oo = 0; oo < 16; ++oo) w2r[oo] = w2t[(o0 + oo) * 64 + p];
  float wloc[30];
  #pragma unroll
  for (int i = 0; i < 30; ++i) wloc[i] = 0.0f;
  #pragma unroll
  for (int g = 0; g < 4; ++g)
    #pragma unroll
    for (int i = 0; i < 2; ++i)
      #pragma unroll
      for (int j = 0; j < 2; ++j) {
        const int s = sg[g * 4 + i * 2 + j];
        #pragma unroll
        for (int c = 0; c < 3; ++c) {
          const int k = (c + 3 * g) * 4 + i * 2 + j;   // w1 flat index over (12,2,2)
          float wk = 0.0f;
          #pragma unroll
          for (int oo = 0; oo < 16; ++oo)
            wk = fmaf(w2r[oo], w1l[(o0 + oo) * 48 + k], wk);  // w1l read is broadcast
          wloc[s * 3 + c] += wk;
        }
      }
  #pragma unroll
  for (int i = 0; i < 30; ++i) part[grp][i][p] = wloc[i];
  float sb = 0.0f;
  #pragma unroll
  for (int oo = 0; oo < 16; ++oo) sb = fmaf(w2r[oo], b1l[o0 + oo], sb);
  bpart[grp][p] = sb;
  __syncthreads();
  const float* p0 = &part[0][0][0];
  for (int idx = t; idx < 30 * 64; idx += 256)
    wn[idx] = p0[idx] + p0[1920 + idx] + p0[3840 + idx] + p0[5760 + idx];
  if (t < 64) bb[t] = b2[t] + bpart[0][t] + bpart[1][t] + bpart[2][t] + bpart[3][t];
}

// ---------------- topk: exact 10-NN (f64-ranked), latency-tolerant restructure --------
// 1024-thread blocks (16 waves, 1 block/CU -> 4 waves/SIMD, 2x R4's occupancy). Each
// wave: 8 rows in ONE batch. All per-row serial phases are interleaved 8-wide
// (iteration-major) so dependency chains overlap:
//   pass1: per-candidate ds_read_b128 serves 8 rows (pair-packed f32x2); lane minima.
//   tau:   ballot-bisection, ITERATION-major over the 8 independent rows (8-way ILP).
//          Invariant count(<=hi)>=10 -> hi is a valid upper bound on the row's
//          10th-smallest f32 key; 24 iters -> <=256-ulp overshoot (negligible).
//   pass2: recompute keys (VALU is cheap; caching 512 keys would blow VGPRs), push
//          survivors (key <= tau+slack) to per-wave/per-row LDS buffers.
//   pass3: f64 re-rank (matches np-f64 reference ordering; self -> exact 0.0) by
//          rank-counting with readlane, J-MAJOR across the 8 rows; rank = output slot.
// Key = sqm - 2*dot (row-constant sqn dropped: order-preserving). Slack 2e-4 >>
// |f32-f64| (~4e-5 at |coord|<~4.7), so the f64-top-10 provably survives the filter.
__global__ __launch_bounds__(1024, 4) void topk_kernel(const float* __restrict__ pos,
                                                       int* __restrict__ idx_out) {
  __shared__ float4 pts[NPTS];        // (x,y,z,sq_f32): 64 KB
  __shared__ int cnt[16][8];
  __shared__ int bufi[16][8][64];     // 32 KB

  const int b = blockIdx.y, tid = threadIdx.x, lane = tid & 63, wv = tid >> 6;
  const float* pb = pos + (size_t)b * 3 * NPTS;
  for (int i = tid; i < NPTS; i += 1024) {
    float x = pb[i], y = pb[i + NPTS], z = pb[i + 2 * NPTS];
    float sq = __fadd_rn(__fadd_rn(__fmul_rn(x, x), __fmul_rn(y, y)), __fmul_rn(z, z));
    pts[i] = make_float4(x, y, z, sq);
  }
  __syncthreads();

  const int n0 = blockIdx.x * 128 + wv * 8;

  // load 8 queries, pair-packed (wave-uniform broadcast reads)
  f32x2 qx[4], qy[4], qz[4], dmin[4];
  #pragma unroll
  for (int pp = 0; pp < 4; ++pp) {
    float4 qa = pts[n0 + 2 * pp], qb = pts[n0 + 2 * pp + 1];
    qx[pp].x = qa.x; qx[pp].y = qb.x;
    qy[pp].x = qa.y; qy[pp].y = qb.y;
    qz[pp].x = qa.z; qz[pp].y = qb.z;
    dmin[pp].x = INFINITY; dmin[pp].y = INFINITY;
  }

  // ---- pass 1: per-row lane minima (1 LDS b128 per candidate serves 8 rows) ----
  #pragma unroll 8
  for (int k = 0; k < 64; ++k) {
    float4 p = pts[k * 64 + lane];
    #pragma unroll
    for (int pp = 0; pp < 4; ++pp) {
      f32x2 dot = qx[pp] * p.x + qy[pp] * p.y + qz[pp] * p.z;
      f32x2 key = (-2.0f) * dot + p.w;
      dmin[pp] = __builtin_elementwise_min(dmin[pp], key);
    }
  }

  // ---- tau: ballot bisection, iteration-major (8 independent chains in flight) ----
  unsigned um[8], lo[8], hi[8];
  #pragma unroll
  for (int r = 0; r < 8; ++r) {
    float dm = (r & 1) ? dmin[r >> 1].y : dmin[r >> 1].x;
    unsigned ub = __float_as_uint(dm);
    um[r] = (ub & 0x80000000u) ? ~ub : (ub | 0x80000000u);
    lo[r] = 0u; hi[r] = 0xFFFFFFFFu;
  }
  #pragma unroll 1
  for (int it = 0; it < 24; ++it) {
    #pragma unroll
    for (int r = 0; r < 8; ++r) {
      unsigned mid = lo[r] + ((hi[r] - lo[r]) >> 1);
      int c10 = __popcll(__ballot(um[r] <= mid));
      if (c10 >= NSMP) hi[r] = mid; else lo[r] = mid + 1;
    }
  }
  float tx[8];
  #pragma unroll
  for (int r = 0; r < 8; ++r) {
    unsigned tb = (hi[r] & 0x80000000u) ? (hi[r] ^ 0x80000000u) : ~hi[r];
    float tf = __uint_as_float(tb);
    tx[r] = __fadd_rn(__fadd_rn(tf, 2e-4f), __fmul_rn(fabsf(tf), 1e-5f));
  }

  if (lane < 8) cnt[wv][lane] = 0;     // same-wave DS ops are in-order

  // ---- pass 2: recompute keys, push survivors per row ----
  #pragma unroll 4
  for (int k = 0; k < 64; ++k) {
    float4 p = pts[k * 64 + lane];
    #pragma unroll
    for (int pp = 0; pp < 4; ++pp) {
      f32x2 dot = qx[pp] * p.x + qy[pp] * p.y + qz[pp] * p.z;
      f32x2 key = (-2.0f) * dot + p.w;
      if (key.x <= tx[2 * pp]) {
        int ps = atomicAdd(&cnt[wv][2 * pp], 1);
        if (ps < 64) bufi[wv][2 * pp][ps] = k * 64 + lane;
      }
      if (key.y <= tx[2 * pp + 1]) {
        int ps = atomicAdd(&cnt[wv][2 * pp + 1], 1);
        if (ps < 64) bufi[wv][2 * pp + 1][ps] = k * 64 + lane;
      }
    }
  }

  // ---- pass 3: f64 re-rank via readlane rank-count, j-major (8-way ILP) ----
  int c[8], si[8], rank[8];
  double dd[8];
  int cmax = 0;
  #pragma unroll
  for (int r = 0; r < 8; ++r) {
    c[r] = __builtin_amdgcn_readfirstlane(cnt[wv][r]);
    if (c[r] > 64) c[r] = 64;
    cmax = (c[r] > cmax) ? c[r] : cmax;
    rank[r] = 0;
  }
  #pragma unroll
  for (int r = 0; r < 8; ++r) {
    float qxr = (r & 1) ? qx[r >> 1].y : qx[r >> 1].x;
    float qyr = (r & 1) ? qy[r >> 1].y : qy[r >> 1].x;
    float qzr = (r & 1) ? qz[r >> 1].y : qz[r >> 1].x;
    if (lane < c[r]) {
      si[r] = bufi[wv][r][lane];
      float4 p = pts[si[r]];
      double dqx = (double)qxr, dqy = (double)qyr, dqz = (double)qzr;
      double px = (double)p.x, py = (double)p.y, pz = (double)p.z;
      double dot = dqx * px + dqy * py + dqz * pz;
      double sqn = dqx * dqx + dqy * dqy + dqz * dqz;
      double sqm = px * px + py * py + pz * pz;
      dd[r] = (sqn - 2.0 * dot) + sqm;             // self -> exactly 0.0
    } else { dd[r] = (double)INFINITY; si[r] = 0x7FFFFFFF; }
  }
  #pragma unroll 1
  for (int j = 0; j < cmax; ++j) {
    #pragma unroll
    for (int r = 0; r < 8; ++r) {
      int jlo = __builtin_amdgcn_readlane(__double2loint(dd[r]), j);
      int jhi = __builtin_amdgcn_readlane(__double2hiint(dd[r]), j);
      int ji  = __builtin_amdgcn_readlane(si[r], j);
      double jd = __hiloint2double(jhi, jlo);
      // lanes >= c[r] hold +INF -> never counted; no j<c[r] predicate needed
      if (jd < dd[r] || (jd == dd[r] && ji < si[r])) ++rank[r];
    }
  }
  #pragma unroll
  for (int r = 0; r < 8; ++r)
    if (lane < c[r] && rank[r] < NSMP)
      idx_out[((size_t)b * NPTS + n0 + r) * NSMP + rank[r]] = si[r];
}

// ---------------- mlp: out[b,p,n] = bb[p] + sum_{s,c} Wn[s*3+c][p]*pos[b,c,idx_s] ----
// 128-thread blocks x 256 blocks: one block per CU (all CUs busy).
__global__ __launch_bounds__(128) void mlp_kernel(const float* __restrict__ pos,
                                                  const int* __restrict__ nbr,
                                                  const float* __restrict__ wn,
                                                  const float* __restrict__ bbg,
                                                  float* __restrict__ out) {
  __shared__ __align__(16) float wl[30 * 64];
  __shared__ float bl[64];
  const int b = blockIdx.y;
  const int tid = threadIdx.x;
  for (int i = tid; i < 30 * 64; i += 128) wl[i] = wn[i];
  if (tid < 64) bl[tid] = bbg[tid];
  __syncthreads();

  const int n = blockIdx.x * 128 + tid;
  const float* pb = pos + (size_t)b * 3 * NPTS;
  const int* ip = nbr + ((size_t)b * NPTS + n) * NSMP;

  float pxyz[30];
  #pragma unroll
  for (int s = 0; s < NSMP; ++s) {
    int i = ip[s];
    pxyz[s * 3 + 0] = pb[i];
    pxyz[s * 3 + 1] = pb[i + NPTS];
    pxyz[s * 3 + 2] = pb[i + 2 * NPTS];
  }

  float acc[64];
  #pragma unroll
  for (int p = 0; p < 64; ++p) acc[p] = bl[p];
  #pragma unroll
  for (int sc = 0; sc < 30; ++sc) {
    float vv = pxyz[sc];
    const float4* w4 = (const float4*)(&wl[sc * 64]);   // wave-uniform broadcast b128
    #pragma unroll
    for (int pq = 0; pq < 16; ++pq) {
      float4 w = w4[pq];
      acc[pq * 4 + 0] = fmaf(w.x, vv, acc[pq * 4 + 0]);
      acc[pq * 4 + 1] = fmaf(w.y, vv, acc[pq * 4 + 1]);
      acc[pq * 4 + 2] = fmaf(w.z, vv, acc[pq * 4 + 2]);
      acc[pq * 4 + 3] = fmaf(w.w, vv, acc[pq * 4 + 3]);
    }
  }

  float* ob = out + ((size_t)b * 64) * NPTS + n;        // out layout (B,64,N)
  #pragma unroll
  for (int p = 0; p < 64; ++p) ob[p * NPTS] = acc[p];   // coalesced across lanes
}

extern "C" void kernel_launch(void* const* d_in, const int* in_sizes, int n_in,
                              void* d_out, int out_size, void* d_ws, size_t ws_size,
                              hipStream_t stream) {
  (void)in_sizes; (void)n_in; (void)out_size; (void)ws_size;
  const float* pos = (const float*)d_in[0];
  const float* w1  = (const float*)d_in[1];
  const float* b1  = (const float*)d_in[2];
  const float* w2  = (const float*)d_in[3];
  const float* b2  = (const float*)d_in[4];
  float* out = (float*)d_out;

  // workspace layout: [0, 1310720) idx (8*4096*10 int); then Wn (30*64 f32); then bb (64 f32)
  int*   nbr = (int*)d_ws;
  float* wn  = (float*)((char*)d_ws + 1310720);
  float* bb  = (float*)((char*)d_ws + 1310720 + 30 * 64 * 4);

  prep_kernel<<<dim3(1), dim3(256), 0, stream>>>(w1, b1, w2, b2, wn, bb);
  topk_kernel<<<dim3(32, 8), dim3(1024), 0, stream>>>(pos, nbr);
  mlp_kernel<<<dim3(32, 8), dim3(128), 0, stream>>>(pos, nbr, wn, bb, out);
}

// Round 6
// 135.712 us; speedup vs baseline: 1.6648x; 1.1073x over previous
//
#include <hip/hip_runtime.h>
#include <math.h>

#define NPTS 4096
#define NSMP 10

typedef float f32x2 __attribute__((ext_vector_type(2)));

// ---------------- prep: fuse (w1,b1,w2,b2) -> Wn[30][64] ([s*3+c][p]), bb[64] ----------
// out[p] = bb[p] + sum_{s,c} Wn[s*3+c][p] * pos[b,c,idx_s]  (no nonlinearity -> legal).
__global__ __launch_bounds__(256) void prep_kernel(
    const float* __restrict__ w1, const float* __restrict__ b1,
    const float* __restrict__ w2, const float* __restrict__ b2,
    float* __restrict__ wn, float* __restrict__ bb) {
  __shared__ float w1l[64 * 48];      // 12 KB, [o][k]
  __shared__ float w2t[64 * 64];      // 16 KB, transposed [o][p] (lane reads stride-1)
  __shared__ float b1l[64];
  __shared__ float part[4][30][64];   // 30 KB
  __shared__ float bpart[4][64];
  const int t = threadIdx.x, p = t & 63, grp = t >> 6, o0 = grp * 16;
  for (int idx = t; idx < 64 * 48; idx += 256) w1l[idx] = w1[idx];
  for (int idx = t; idx < 64 * 64; idx += 256) w2t[(idx & 63) * 64 + (idx >> 6)] = w2[idx];
  if (t < 64) b1l[t] = b1[t];
  __syncthreads();

  const int sg[16] = {0,2,4,6, 3,5,7,9, 1,3,5,7, 2,4,6,8};
  float w2r[16];
  #pragma unroll
  for (int oo = 0; oo < 16; ++oo) w2r[oo] = w2t[(o0 + oo) * 64 + p];
  float wloc[30];
  #pragma unroll
  for (int i = 0; i < 30; ++i) wloc[i] = 0.0f;
  #pragma unroll
  for (int g = 0; g < 4; ++g)
    #pragma unroll
    for (int i = 0; i < 2; ++i)
      #pragma unroll
      for (int j = 0; j < 2; ++j) {
        const int s = sg[g * 4 + i * 2 + j];
        #pragma unroll
        for (int c = 0; c < 3; ++c) {
          const int k = (c + 3 * g) * 4 + i * 2 + j;   // w1 flat index over (12,2,2)
          float wk = 0.0f;
          #pragma unroll
          for (int oo = 0; oo < 16; ++oo)
            wk = fmaf(w2r[oo], w1l[(o0 + oo) * 48 + k], wk);  // w1l read is broadcast
          wloc[s * 3 + c] += wk;
        }
      }
  #pragma unroll
  for (int i = 0; i < 30; ++i) part[grp][i][p] = wloc[i];
  float sb = 0.0f;
  #pragma unroll
  for (int oo = 0; oo < 16; ++oo) sb = fmaf(w2r[oo], b1l[o0 + oo], sb);
  bpart[grp][p] = sb;
  __syncthreads();
  const float* p0 = &part[0][0][0];
  for (int idx = t; idx < 30 * 64; idx += 256)
    wn[idx] = p0[idx] + p0[1920 + idx] + p0[3840 + idx] + p0[5760 + idx];
  if (t < 64) bb[t] = b2[t] + bpart[0][t] + bpart[1][t] + bpart[2][t] + bpart[3][t];
}

// ---------------- fused topk + mlp: exact 10-NN (f64-ranked) + linear epilogue --------
// 1024-thread blocks, 1/CU, 16 waves; each wave owns 8 rows. Phases (per wave):
//   pass1: per-candidate ds_read_b128 serves 8 rows; key = fma-chain
//          key = ((p.w + qx2*px) + qy2*py-terms) via 3 pk-fma (qx2 = -2*qx folded);
//          track per-row lane minima. Key order == d2 order (row-const sqn dropped).
//   tau:   ballot-bisection on monotone-u32, iteration-major (8-way ILP), 20 iters.
//          Invariant count(<=hi)>=10 keeps hi a valid upper bound on the row's
//          10th-smallest key (<=1e-3 loose -> ~0.3 extra survivors/row).
//   pass2: recompute keys (identical formula -> filter is provably a superset:
//          slack 2e-4 >> |f32-f64| ~4e-5), push survivor indices to LDS.
//   pass3: f64 re-rank (matches np-f64 reference ordering; self -> exact 0.0) by
//          readlane rank-count, j-major; rank<10 lanes write idx to LDS nbrL.
//   epi:   (fused mlp) per row: broadcast-gather the 10 neighbors' float4 from pts,
//          acc[p=lane] += Wn[sc][lane]*coord in same fma order as before ->
//          bit-identical output. Lane p stores 8 consecutive n as 2 float4.
// No global idx buffer, no separate mlp kernel.
__global__ __launch_bounds__(1024, 4) void topk_kernel(const float* __restrict__ pos,
                                                       const float* __restrict__ wng,
                                                       const float* __restrict__ bbg,
                                                       float* __restrict__ out) {
  __shared__ float4 pts[NPTS];        // (x,y,z,sq_f32): 64 KB
  __shared__ int cnt[16][8];
  __shared__ int bufi[16][8][64];     // 32 KB
  __shared__ int nbrL[16][8][NSMP];   // 5 KB

  const int b = blockIdx.y, tid = threadIdx.x, lane = tid & 63, wv = tid >> 6;
  const float* pb = pos + (size_t)b * 3 * NPTS;
  for (int i = tid; i < NPTS; i += 1024) {
    float x = pb[i], y = pb[i + NPTS], z = pb[i + 2 * NPTS];
    float sq = __fadd_rn(__fadd_rn(__fmul_rn(x, x), __fmul_rn(y, y)), __fmul_rn(z, z));
    pts[i] = make_float4(x, y, z, sq);
  }
  // per-lane Wn column + bias (31 VGPRs), overlap with staging
  float wnr[30];
  #pragma unroll
  for (int sc = 0; sc < 30; ++sc) wnr[sc] = wng[sc * 64 + lane];
  const float blv = bbg[lane];
  __syncthreads();

  const int n0 = blockIdx.x * 128 + wv * 8;

  // load 8 queries; fold -2 into q (filter-only arithmetic; pass3 re-ranks in f64)
  f32x2 qx2[4], qy2[4], qz2[4], dmin[4];
  #pragma unroll
  for (int pp = 0; pp < 4; ++pp) {
    float4 qa = pts[n0 + 2 * pp], qb = pts[n0 + 2 * pp + 1];
    qx2[pp].x = -2.0f * qa.x; qx2[pp].y = -2.0f * qb.x;
    qy2[pp].x = -2.0f * qa.y; qy2[pp].y = -2.0f * qb.y;
    qz2[pp].x = -2.0f * qa.z; qz2[pp].y = -2.0f * qb.z;
    dmin[pp].x = INFINITY; dmin[pp].y = INFINITY;
  }

  // ---- pass 1: per-row lane minima (1 LDS b128 per candidate serves 8 rows) ----
  #pragma unroll 8
  for (int k = 0; k < 64; ++k) {
    float4 p = pts[k * 64 + lane];
    #pragma unroll
    for (int pp = 0; pp < 4; ++pp) {
      f32x2 key = qx2[pp] * p.x + p.w;          // pk_fma
      key = qy2[pp] * p.y + key;                // pk_fma
      key = qz2[pp] * p.z + key;                // pk_fma
      dmin[pp] = __builtin_elementwise_min(dmin[pp], key);
    }
  }

  // ---- tau: ballot bisection, iteration-major (8 independent chains) ----
  unsigned um[8], lo[8], hi[8];
  #pragma unroll
  for (int r = 0; r < 8; ++r) {
    float dm = (r & 1) ? dmin[r >> 1].y : dmin[r >> 1].x;
    unsigned ub = __float_as_uint(dm);
    um[r] = (ub & 0x80000000u) ? ~ub : (ub | 0x80000000u);
    lo[r] = 0u; hi[r] = 0xFFFFFFFFu;
  }
  #pragma unroll 1
  for (int it = 0; it < 20; ++it) {
    #pragma unroll
    for (int r = 0; r < 8; ++r) {
      unsigned mid = lo[r] + ((hi[r] - lo[r]) >> 1);
      int c10 = __popcll(__ballot(um[r] <= mid));
      if (c10 >= NSMP) hi[r] = mid; else lo[r] = mid + 1;
    }
  }
  float tx[8];
  #pragma unroll
  for (int r = 0; r < 8; ++r) {
    unsigned tb = (hi[r] & 0x80000000u) ? (hi[r] ^ 0x80000000u) : ~hi[r];
    float tf = __uint_as_float(tb);
    tx[r] = __fadd_rn(__fadd_rn(tf, 2e-4f), __fmul_rn(fabsf(tf), 1e-5f));
  }

  if (lane < 8) cnt[wv][lane] = 0;     // same-wave DS ops are in-order

  // ---- pass 2: recompute keys (identical formula), push survivors per row ----
  #pragma unroll 4
  for (int k = 0; k < 64; ++k) {
    float4 p = pts[k * 64 + lane];
    #pragma unroll
    for (int pp = 0; pp < 4; ++pp) {
      f32x2 key = qx2[pp] * p.x + p.w;
      key = qy2[pp] * p.y + key;
      key = qz2[pp] * p.z + key;
      if (key.x <= tx[2 * pp]) {
        int ps = atomicAdd(&cnt[wv][2 * pp], 1);
        if (ps < 64) bufi[wv][2 * pp][ps] = k * 64 + lane;
      }
      if (key.y <= tx[2 * pp + 1]) {
        int ps = atomicAdd(&cnt[wv][2 * pp + 1], 1);
        if (ps < 64) bufi[wv][2 * pp + 1][ps] = k * 64 + lane;
      }
    }
  }

  // ---- pass 3: f64 re-rank via readlane rank-count, j-major (8-way ILP) ----
  int c[8], si[8], rank[8];
  double dd[8];
  int cmax = 0;
  #pragma unroll
  for (int r = 0; r < 8; ++r) {
    c[r] = __builtin_amdgcn_readfirstlane(cnt[wv][r]);
    if (c[r] > 64) c[r] = 64;
    cmax = (c[r] > cmax) ? c[r] : cmax;
    rank[r] = 0;
  }
  #pragma unroll
  for (int r = 0; r < 8; ++r) {
    float4 qa = pts[n0 + r];
    if (lane < c[r]) {
      si[r] = bufi[wv][r][lane];
      float4 p = pts[si[r]];
      double dqx = (double)qa.x, dqy = (double)qa.y, dqz = (double)qa.z;
      double px = (double)p.x, py = (double)p.y, pz = (double)p.z;
      double dot = dqx * px + dqy * py + dqz * pz;
      double sqn = dqx * dqx + dqy * dqy + dqz * dqz;
      double sqm = px * px + py * py + pz * pz;
      dd[r] = (sqn - 2.0 * dot) + sqm;             // self -> exactly 0.0
    } else { dd[r] = (double)INFINITY; si[r] = 0x7FFFFFFF; }
  }
  #pragma unroll 1
  for (int j = 0; j < cmax; ++j) {
    #pragma unroll
    for (int r = 0; r < 8; ++r) {
      int jlo = __builtin_amdgcn_readlane(__double2loint(dd[r]), j);
      int jhi = __builtin_amdgcn_readlane(__double2hiint(dd[r]), j);
      int ji  = __builtin_amdgcn_readlane(si[r], j);
      double jd = __hiloint2double(jhi, jlo);
      if (jd < dd[r] || (jd == dd[r] && ji < si[r])) ++rank[r];
    }
  }
  #pragma unroll
  for (int r = 0; r < 8; ++r)
    if (lane < c[r] && rank[r] < NSMP)
      nbrL[wv][r][rank[r]] = si[r];

  // ---- epilogue (fused mlp): out[b, p=lane, n0+r] ----
  // Same fma order (sc ascending) as the old mlp kernel -> bit-identical output.
  float acc[8];
  #pragma unroll
  for (int r = 0; r < 8; ++r) acc[r] = blv;
  #pragma unroll 1
  for (int r = 0; r < 8; ++r) {
    float a = acc[r];
    #pragma unroll
    for (int s = 0; s < NSMP; ++s) {
      int id = nbrL[wv][r][s];        // uniform -> broadcast ds_read
      float4 pv = pts[id];
      a = fmaf(wnr[s * 3 + 0], pv.x, a);
      a = fmaf(wnr[s * 3 + 1], pv.y, a);
      a = fmaf(wnr[s * 3 + 2], pv.z, a);
    }
    acc[r] = a;
  }
  float* ob = out + ((size_t)b * 64 + lane) * NPTS + n0;   // out layout (B,64,N)
  float4 v0 = make_float4(acc[0], acc[1], acc[2], acc[3]);
  float4 v1 = make_float4(acc[4], acc[5], acc[6], acc[7]);
  *(float4*)(ob)     = v0;
  *(float4*)(ob + 4) = v1;
}

extern "C" void kernel_launch(void* const* d_in, const int* in_sizes, int n_in,
                              void* d_out, int out_size, void* d_ws, size_t ws_size,
                              hipStream_t stream) {
  (void)in_sizes; (void)n_in; (void)out_size; (void)ws_size;
  const float* pos = (const float*)d_in[0];
  const float* w1  = (const float*)d_in[1];
  const float* b1  = (const float*)d_in[2];
  const float* w2  = (const float*)d_in[3];
  const float* b2  = (const float*)d_in[4];
  float* out = (float*)d_out;

  // workspace: Wn (30*64 f32) then bb (64 f32)
  float* wn = (float*)d_ws;
  float* bb = (float*)((char*)d_ws + 30 * 64 * 4);

  prep_kernel<<<dim3(1), dim3(256), 0, stream>>>(w1, b1, w2, b2, wn, bb);
  topk_kernel<<<dim3(32, 8), dim3(1024), 0, stream>>>(pos, wn, bb, out);
}

// Round 7
// 133.795 us; speedup vs baseline: 1.6886x; 1.0143x over previous
//
#include <hip/hip_runtime.h>
#include <math.h>

#define NPTS 4096
#define NSMP 10

typedef float f32x2 __attribute__((ext_vector_type(2)));

// ---------------- prep: fuse (w1,b1,w2,b2) -> Wn[30][64] ([s*3+c][p]), bb[64] ----------
// out[p] = bb[p] + sum_{s,c} Wn[s*3+c][p] * pos[b,c,idx_s]  (no nonlinearity -> legal).
__global__ __launch_bounds__(256) void prep_kernel(
    const float* __restrict__ w1, const float* __restrict__ b1,
    const float* __restrict__ w2, const float* __restrict__ b2,
    float* __restrict__ wn, float* __restrict__ bb) {
  __shared__ float w1l[64 * 48];      // 12 KB, [o][k]
  __shared__ float w2t[64 * 64];      // 16 KB, transposed [o][p] (lane reads stride-1)
  __shared__ float b1l[64];
  __shared__ float part[4][30][64];   // 30 KB
  __shared__ float bpart[4][64];
  const int t = threadIdx.x, p = t & 63, grp = t >> 6, o0 = grp * 16;
  for (int idx = t; idx < 64 * 48; idx += 256) w1l[idx] = w1[idx];
  for (int idx = t; idx < 64 * 64; idx += 256) w2t[(idx & 63) * 64 + (idx >> 6)] = w2[idx];
  if (t < 64) b1l[t] = b1[t];
  __syncthreads();

  const int sg[16] = {0,2,4,6, 3,5,7,9, 1,3,5,7, 2,4,6,8};
  float w2r[16];
  #pragma unroll
  for (int oo = 0; oo < 16; ++oo) w2r[oo] = w2t[(o0 + oo) * 64 + p];
  float wloc[30];
  #pragma unroll
  for (int i = 0; i < 30; ++i) wloc[i] = 0.0f;
  #pragma unroll
  for (int g = 0; g < 4; ++g)
    #pragma unroll
    for (int i = 0; i < 2; ++i)
      #pragma unroll
      for (int j = 0; j < 2; ++j) {
        const int s = sg[g * 4 + i * 2 + j];
        #pragma unroll
        for (int c = 0; c < 3; ++c) {
          const int k = (c + 3 * g) * 4 + i * 2 + j;   // w1 flat index over (12,2,2)
          float wk = 0.0f;
          #pragma unroll
          for (int oo = 0; oo < 16; ++oo)
            wk = fmaf(w2r[oo], w1l[(o0 + oo) * 48 + k], wk);  // w1l read is broadcast
          wloc[s * 3 + c] += wk;
        }
      }
  #pragma unroll
  for (int i = 0; i < 30; ++i) part[grp][i][p] = wloc[i];
  float sb = 0.0f;
  #pragma unroll
  for (int oo = 0; oo < 16; ++oo) sb = fmaf(w2r[oo], b1l[o0 + oo], sb);
  bpart[grp][p] = sb;
  __syncthreads();
  const float* p0 = &part[0][0][0];
  for (int idx = t; idx < 30 * 64; idx += 256)
    wn[idx] = p0[idx] + p0[1920 + idx] + p0[3840 + idx] + p0[5760 + idx];
  if (t < 64) bb[t] = b2[t] + bpart[0][t] + bpart[1][t] + bpart[2][t] + bpart[3][t];
}

// ---------------- fused topk + mlp, 2-blocks/CU edition ------------------------------
// 1024 threads (16 waves), grid 64x8 = 512 blocks = 2/CU -> 32 waves/CU (2x R6).
// LDS/block 74.75 KB (x2 = 149.5 <= 160). Wave owns 4 rows; block owns 64 rows.
//   pts: packed float3 (48 KB); sq recomputed per candidate (filter-only; pass1 and
//        pass2 use the IDENTICAL formula -> superset property intact; ranking is f64).
//   pass1: per-candidate float3 LDS read serves 4 rows (2x f32x2 pk-fma chains);
//          per-row lane minima. Key = sqm - 2*dot (row-const sqn dropped).
//   tau:  ballot-bisection on monotone-u32, iteration-major, 24 iters. Invariant
//         count(<=hi)>=10 -> hi >= row's 10th-smallest key. Slack covers f32-vs-f64.
//   pass2: recompute keys, push survivors into per-wave bufi slice (cap 64).
//   pass3: f64 re-rank (np-f64 reference order; self -> exact 0.0) via readlane
//          rank-count, j-major. Unchanged from R6 -> bit-identical indices.
//   epi:  acc[p=lane] over 10 nbrs (Wn from LDS, same fma order -> bit-identical),
//         then per-wave LDS transpose slice (aliases its own dead bufi slice;
//         same-wave DS in-order -> no barrier), one __syncthreads, and
//         float4 stores of 4 consecutive n -> coalesced 256B runs, no partial lines.
__global__ __launch_bounds__(1024, 8) void topk_kernel(const float* __restrict__ pos,
                                                       const float* __restrict__ wng,
                                                       const float* __restrict__ bbg,
                                                       float* __restrict__ out) {
  __shared__ float pts3[NPTS * 3];    // 48 KB packed (x,y,z)
  __shared__ float trans[16 * 260];   // 16.25 KB; per-wave 260-float slice (alias: bufi)
  __shared__ float wl[30 * 64];       // 7.5 KB Wn
  __shared__ float bl[64];
  __shared__ int   nbrL[16][4][NSMP]; // 2.5 KB
  __shared__ int   cnt[16][4];

  const int b = blockIdx.y, tid = threadIdx.x, lane = tid & 63, wv = tid >> 6;
  const float* pb = pos + (size_t)b * 3 * NPTS;
  for (int i = tid; i < NPTS; i += 1024) {
    pts3[3 * i + 0] = pb[i];
    pts3[3 * i + 1] = pb[i + NPTS];
    pts3[3 * i + 2] = pb[i + 2 * NPTS];
  }
  for (int i = tid; i < 30 * 64; i += 1024) wl[i] = wng[i];
  if (tid < 64) bl[tid] = bbg[tid];
  __syncthreads();

  const int nb = blockIdx.x * 64;       // block's first row
  const int n0 = nb + wv * 4;           // wave's first row
  float* transF = &trans[wv * 260];     // this wave's private slice
  int*   bufiW  = (int*)transF;         // survivor buffer: r*64+slot (256 ints <= 260)

  // 4 queries, pair-packed, -2 folded (filter-only arithmetic)
  f32x2 qx2[2], qy2[2], qz2[2], dmin[2];
  #pragma unroll
  for (int pp = 0; pp < 2; ++pp) {
    int na = n0 + 2 * pp;
    qx2[pp].x = -2.0f * pts3[3 * na + 0]; qx2[pp].y = -2.0f * pts3[3 * na + 3];
    qy2[pp].x = -2.0f * pts3[3 * na + 1]; qy2[pp].y = -2.0f * pts3[3 * na + 4];
    qz2[pp].x = -2.0f * pts3[3 * na + 2]; qz2[pp].y = -2.0f * pts3[3 * na + 5];
    dmin[pp].x = INFINITY; dmin[pp].y = INFINITY;
  }

  // ---- pass 1: per-row lane minima ----
  #pragma unroll 4
  for (int k = 0; k < 64; ++k) {
    int m = k * 64 + lane;
    float x = pts3[3 * m], y = pts3[3 * m + 1], z = pts3[3 * m + 2];
    float sq = fmaf(z, z, fmaf(y, y, x * x));
    f32x2 sq2; sq2.x = sq; sq2.y = sq;
    #pragma unroll
    for (int pp = 0; pp < 2; ++pp) {
      f32x2 key = qx2[pp] * x + sq2;
      key = qy2[pp] * y + key;
      key = qz2[pp] * z + key;
      dmin[pp] = __builtin_elementwise_min(dmin[pp], key);
    }
  }

  // ---- tau: ballot bisection, iteration-major (4 chains in flight) ----
  unsigned um[4], lo[4], hi[4];
  #pragma unroll
  for (int r = 0; r < 4; ++r) {
    float dm = (r & 1) ? dmin[r >> 1].y : dmin[r >> 1].x;
    unsigned ub = __float_as_uint(dm);
    um[r] = (ub & 0x80000000u) ? ~ub : (ub | 0x80000000u);
    lo[r] = 0u; hi[r] = 0xFFFFFFFFu;
  }
  #pragma unroll 1
  for (int it = 0; it < 24; ++it) {
    #pragma unroll
    for (int r = 0; r < 4; ++r) {
      unsigned mid = lo[r] + ((hi[r] - lo[r]) >> 1);
      int c10 = __popcll(__ballot(um[r] <= mid));
      if (c10 >= NSMP) hi[r] = mid; else lo[r] = mid + 1;
    }
  }
  float tx[4];
  #pragma unroll
  for (int r = 0; r < 4; ++r) {
    unsigned tb = (hi[r] & 0x80000000u) ? (hi[r] ^ 0x80000000u) : ~hi[r];
    float tf = __uint_as_float(tb);
    tx[r] = __fadd_rn(__fadd_rn(tf, 2e-4f), __fmul_rn(fabsf(tf), 1e-5f));
  }

  if (lane < 4) cnt[wv][lane] = 0;     // same-wave DS ops are in-order

  // ---- pass 2: recompute keys (identical formula), push survivors ----
  #pragma unroll 4
  for (int k = 0; k < 64; ++k) {
    int m = k * 64 + lane;
    float x = pts3[3 * m], y = pts3[3 * m + 1], z = pts3[3 * m + 2];
    float sq = fmaf(z, z, fmaf(y, y, x * x));
    f32x2 sq2; sq2.x = sq; sq2.y = sq;
    #pragma unroll
    for (int pp = 0; pp < 2; ++pp) {
      f32x2 key = qx2[pp] * x + sq2;
      key = qy2[pp] * y + key;
      key = qz2[pp] * z + key;
      if (key.x <= tx[2 * pp]) {
        int ps = atomicAdd(&cnt[wv][2 * pp], 1);
        if (ps < 64) bufiW[(2 * pp) * 64 + ps] = m;
      }
      if (key.y <= tx[2 * pp + 1]) {
        int ps = atomicAdd(&cnt[wv][2 * pp + 1], 1);
        if (ps < 64) bufiW[(2 * pp + 1) * 64 + ps] = m;
      }
    }
  }

  // ---- pass 3: f64 re-rank via readlane rank-count, j-major ----
  int c[4], si[4], rank[4];
  double dd[4];
  int cmax = 0;
  #pragma unroll
  for (int r = 0; r < 4; ++r) {
    c[r] = __builtin_amdgcn_readfirstlane(cnt[wv][r]);
    if (c[r] > 64) c[r] = 64;
    cmax = (c[r] > cmax) ? c[r] : cmax;
    rank[r] = 0;
  }
  #pragma unroll
  for (int r = 0; r < 4; ++r) {
    int nq = n0 + r;
    float qxf = pts3[3 * nq], qyf = pts3[3 * nq + 1], qzf = pts3[3 * nq + 2];
    if (lane < c[r]) {
      si[r] = bufiW[r * 64 + lane];
      float px = pts3[3 * si[r]], py = pts3[3 * si[r] + 1], pz = pts3[3 * si[r] + 2];
      double dqx = (double)qxf, dqy = (double)qyf, dqz = (double)qzf;
      double dpx = (double)px, dpy = (double)py, dpz = (double)pz;
      double dot = dqx * dpx + dqy * dpy + dqz * dpz;
      double sqn = dqx * dqx + dqy * dqy + dqz * dqz;
      double sqm = dpx * dpx + dpy * dpy + dpz * dpz;
      dd[r] = (sqn - 2.0 * dot) + sqm;             // self -> exactly 0.0
    } else { dd[r] = (double)INFINITY; si[r] = 0x7FFFFFFF; }
  }
  #pragma unroll 1
  for (int j = 0; j < cmax; ++j) {
    #pragma unroll
    for (int r = 0; r < 4; ++r) {
      int jlo = __builtin_amdgcn_readlane(__double2loint(dd[r]), j);
      int jhi = __builtin_amdgcn_readlane(__double2hiint(dd[r]), j);
      int ji  = __builtin_amdgcn_readlane(si[r], j);
      double jd = __hiloint2double(jhi, jlo);
      if (jd < dd[r] || (jd == dd[r] && ji < si[r])) ++rank[r];
    }
  }
  #pragma unroll
  for (int r = 0; r < 4; ++r)
    if (lane < c[r] && rank[r] < NSMP)
      nbrL[wv][r][rank[r]] = si[r];

  // ---- epilogue: acc then per-wave transpose slice (bufiW is dead now) ----
  #pragma unroll 1
  for (int r = 0; r < 4; ++r) {
    float a = bl[lane];
    #pragma unroll
    for (int s = 0; s < NSMP; ++s) {
      int id = nbrL[wv][r][s];          // uniform -> broadcast ds_read
      float px = pts3[3 * id], py = pts3[3 * id + 1], pz = pts3[3 * id + 2];
      a = fmaf(wl[(s * 3 + 0) * 64 + lane], px, a);
      a = fmaf(wl[(s * 3 + 1) * 64 + lane], py, a);
      a = fmaf(wl[(s * 3 + 2) * 64 + lane], pz, a);
    }
    transF[r * 65 + lane] = a;          // padded row -> conflict-free
  }
  __syncthreads();

  // coalesced store: thread (p = tid>>4, t16 = tid&15) writes n = nb + 4*t16 .. +3
  {
    int p = tid >> 4, t16 = tid & 15;
    float4 v;
    v.x = trans[t16 * 260 + 0 * 65 + p];
    v.y = trans[t16 * 260 + 1 * 65 + p];
    v.z = trans[t16 * 260 + 2 * 65 + p];
    v.w = trans[t16 * 260 + 3 * 65 + p];
    *(float4*)(out + ((size_t)b * 64 + p) * NPTS + nb + 4 * t16) = v;
  }
}

extern "C" void kernel_launch(void* const* d_in, const int* in_sizes, int n_in,
                              void* d_out, int out_size, void* d_ws, size_t ws_size,
                              hipStream_t stream) {
  (void)in_sizes; (void)n_in; (void)out_size; (void)ws_size;
  const float* pos = (const float*)d_in[0];
  const float* w1  = (const float*)d_in[1];
  const float* b1  = (const float*)d_in[2];
  const float* w2  = (const float*)d_in[3];
  const float* b2  = (const float*)d_in[4];
  float* out = (float*)d_out;

  // workspace: Wn (30*64 f32) then bb (64 f32)
  float* wn = (float*)d_ws;
  float* bb = (float*)((char*)d_ws + 30 * 64 * 4);

  prep_kernel<<<dim3(1), dim3(256), 0, stream>>>(w1, b1, w2, b2, wn, bb);
  topk_kernel<<<dim3(64, 8), dim3(1024), 0, stream>>>(pos, wn, bb, out);
}

// Round 8
// 131.044 us; speedup vs baseline: 1.7241x; 1.0210x over previous
//
#include <hip/hip_runtime.h>
#include <math.h>

#define NPTS 4096
#define NSMP 10

typedef float f32x2 __attribute__((ext_vector_type(2)));

// ---------------- prep: fuse (w1,b1,w2,b2) -> Wn[30][64] ([s*3+c][p]), bb[64] ----------
// out[p] = bb[p] + sum_{s,c} Wn[s*3+c][p] * pos[b,c,idx_s]  (no nonlinearity -> legal).
__global__ __launch_bounds__(256) void prep_kernel(
    const float* __restrict__ w1, const float* __restrict__ b1,
    const float* __restrict__ w2, const float* __restrict__ b2,
    float* __restrict__ wn, float* __restrict__ bb) {
  __shared__ float w1l[64 * 48];      // 12 KB, [o][k]
  __shared__ float w2t[64 * 64];      // 16 KB, transposed [o][p] (lane reads stride-1)
  __shared__ float b1l[64];
  __shared__ float part[4][30][64];   // 30 KB
  __shared__ float bpart[4][64];
  const int t = threadIdx.x, p = t & 63, grp = t >> 6, o0 = grp * 16;
  for (int idx = t; idx < 64 * 48; idx += 256) w1l[idx] = w1[idx];
  for (int idx = t; idx < 64 * 64; idx += 256) w2t[(idx & 63) * 64 + (idx >> 6)] = w2[idx];
  if (t < 64) b1l[t] = b1[t];
  __syncthreads();

  const int sg[16] = {0,2,4,6, 3,5,7,9, 1,3,5,7, 2,4,6,8};
  float w2r[16];
  #pragma unroll
  for (int oo = 0; oo < 16; ++oo) w2r[oo] = w2t[(o0 + oo) * 64 + p];
  float wloc[30];
  #pragma unroll
  for (int i = 0; i < 30; ++i) wloc[i] = 0.0f;
  #pragma unroll
  for (int g = 0; g < 4; ++g)
    #pragma unroll
    for (int i = 0; i < 2; ++i)
      #pragma unroll
      for (int j = 0; j < 2; ++j) {
        const int s = sg[g * 4 + i * 2 + j];
        #pragma unroll
        for (int c = 0; c < 3; ++c) {
          const int k = (c + 3 * g) * 4 + i * 2 + j;   // w1 flat index over (12,2,2)
          float wk = 0.0f;
          #pragma unroll
          for (int oo = 0; oo < 16; ++oo)
            wk = fmaf(w2r[oo], w1l[(o0 + oo) * 48 + k], wk);  // w1l read is broadcast
          wloc[s * 3 + c] += wk;
        }
      }
  #pragma unroll
  for (int i = 0; i < 30; ++i) part[grp][i][p] = wloc[i];
  float sb = 0.0f;
  #pragma unroll
  for (int oo = 0; oo < 16; ++oo) sb = fmaf(w2r[oo], b1l[o0 + oo], sb);
  bpart[grp][p] = sb;
  __syncthreads();
  const float* p0 = &part[0][0][0];
  for (int idx = t; idx < 30 * 64; idx += 256)
    wn[idx] = p0[idx] + p0[1920 + idx] + p0[3840 + idx] + p0[5760 + idx];
  if (t < 64) bb[t] = b2[t] + bpart[0][t] + bpart[1][t] + bpart[2][t] + bpart[3][t];
}

// ---------------- fused topk + mlp, 2-blocks/CU, spill-free edition -------------------
// 1024 threads (16 waves), grid 64x8 = 512 blocks = 2/CU -> 32 waves/CU. LDS 74.75 KB.
// Register-diet vs R7 (R7 spilled ~23 dwords/thread under the 64-VGPR budget of
// __launch_bounds__(1024,8) -> +46 MB scratch traffic):
//   * pass1/pass2 unroll 4 -> 2 (fewer live ds_read temps)
//   * tau via MSB-first radix-select: the candidate prefix is wave-uniform -> SGPRs;
//     only um[4] stays in VGPRs (replaces um/lo/hi = 12 VGPRs of bisection).
//     T = pfx|0xFF >= 10th-smallest lane-min (exact within 256 ulp) -> valid upper
//     bound on the row's 10th-smallest key; slack covers f32-vs-f64 as before.
// Selection semantics (key formula both passes, slack, f64 re-rank) unchanged from
// R6/R7 -> bit-identical output.
__global__ __launch_bounds__(1024, 8) void topk_kernel(const float* __restrict__ pos,
                                                       const float* __restrict__ wng,
                                                       const float* __restrict__ bbg,
                                                       float* __restrict__ out) {
  __shared__ float pts3[NPTS * 3];    // 48 KB packed (x,y,z)
  __shared__ float trans[16 * 260];   // 16.25 KB; per-wave 260-float slice (alias: bufi)
  __shared__ float wl[30 * 64];       // 7.5 KB Wn
  __shared__ float bl[64];
  __shared__ int   nbrL[16][4][NSMP]; // 2.5 KB
  __shared__ int   cnt[16][4];

  const int b = blockIdx.y, tid = threadIdx.x, lane = tid & 63, wv = tid >> 6;
  const float* pb = pos + (size_t)b * 3 * NPTS;
  for (int i = tid; i < NPTS; i += 1024) {
    pts3[3 * i + 0] = pb[i];
    pts3[3 * i + 1] = pb[i + NPTS];
    pts3[3 * i + 2] = pb[i + 2 * NPTS];
  }
  for (int i = tid; i < 30 * 64; i += 1024) wl[i] = wng[i];
  if (tid < 64) bl[tid] = bbg[tid];
  __syncthreads();

  const int nb = blockIdx.x * 64;       // block's first row
  const int n0 = nb + wv * 4;           // wave's first row
  float* transF = &trans[wv * 260];     // this wave's private slice
  int*   bufiW  = (int*)transF;         // survivor buffer: r*64+slot (256 ints <= 260)

  // 4 queries, pair-packed, -2 folded (filter-only arithmetic)
  f32x2 qx2[2], qy2[2], qz2[2], dmin[2];
  #pragma unroll
  for (int pp = 0; pp < 2; ++pp) {
    int na = n0 + 2 * pp;
    qx2[pp].x = -2.0f * pts3[3 * na + 0]; qx2[pp].y = -2.0f * pts3[3 * na + 3];
    qy2[pp].x = -2.0f * pts3[3 * na + 1]; qy2[pp].y = -2.0f * pts3[3 * na + 4];
    qz2[pp].x = -2.0f * pts3[3 * na + 2]; qz2[pp].y = -2.0f * pts3[3 * na + 5];
    dmin[pp].x = INFINITY; dmin[pp].y = INFINITY;
  }

  // ---- pass 1: per-row lane minima ----
  #pragma unroll 2
  for (int k = 0; k < 64; ++k) {
    int m = k * 64 + lane;
    float x = pts3[3 * m], y = pts3[3 * m + 1], z = pts3[3 * m + 2];
    float sq = fmaf(z, z, fmaf(y, y, x * x));
    f32x2 sq2; sq2.x = sq; sq2.y = sq;
    #pragma unroll
    for (int pp = 0; pp < 2; ++pp) {
      f32x2 key = qx2[pp] * x + sq2;
      key = qy2[pp] * y + key;
      key = qz2[pp] * z + key;
      dmin[pp] = __builtin_elementwise_min(dmin[pp], key);
    }
  }

  // ---- tau: MSB-first radix-select; prefix is wave-uniform (SGPRs) ----
  unsigned um[4];
  #pragma unroll
  for (int r = 0; r < 4; ++r) {
    float dm = (r & 1) ? dmin[r >> 1].y : dmin[r >> 1].x;
    unsigned ub = __float_as_uint(dm);
    um[r] = (ub & 0x80000000u) ? ~ub : (ub | 0x80000000u);
  }
  unsigned pfx0 = 0u, pfx1 = 0u, pfx2 = 0u, pfx3 = 0u;
  #pragma unroll 1
  for (int bno = 31; bno >= 8; --bno) {
    const unsigned bit = 1u << bno, ones = bit - 1u;
    if (__popcll(__ballot(um[0] <= (pfx0 | ones))) < NSMP) pfx0 |= bit;
    if (__popcll(__ballot(um[1] <= (pfx1 | ones))) < NSMP) pfx1 |= bit;
    if (__popcll(__ballot(um[2] <= (pfx2 | ones))) < NSMP) pfx2 |= bit;
    if (__popcll(__ballot(um[3] <= (pfx3 | ones))) < NSMP) pfx3 |= bit;
  }
  float tx[4];
  #pragma unroll
  for (int r = 0; r < 4; ++r) {
    unsigned T = ((r == 0) ? pfx0 : (r == 1) ? pfx1 : (r == 2) ? pfx2 : pfx3) | 0xFFu;
    unsigned tb = (T & 0x80000000u) ? (T ^ 0x80000000u) : ~T;
    float tf = __uint_as_float(tb);
    tx[r] = __fadd_rn(__fadd_rn(tf, 2e-4f), __fmul_rn(fabsf(tf), 1e-5f));
  }

  if (lane < 4) cnt[wv][lane] = 0;     // same-wave DS ops are in-order

  // ---- pass 2: recompute keys (identical formula), push survivors ----
  #pragma unroll 2
  for (int k = 0; k < 64; ++k) {
    int m = k * 64 + lane;
    float x = pts3[3 * m], y = pts3[3 * m + 1], z = pts3[3 * m + 2];
    float sq = fmaf(z, z, fmaf(y, y, x * x));
    f32x2 sq2; sq2.x = sq; sq2.y = sq;
    #pragma unroll
    for (int pp = 0; pp < 2; ++pp) {
      f32x2 key = qx2[pp] * x + sq2;
      key = qy2[pp] * y + key;
      key = qz2[pp] * z + key;
      if (key.x <= tx[2 * pp]) {
        int ps = atomicAdd(&cnt[wv][2 * pp], 1);
        if (ps < 64) bufiW[(2 * pp) * 64 + ps] = m;
      }
      if (key.y <= tx[2 * pp + 1]) {
        int ps = atomicAdd(&cnt[wv][2 * pp + 1], 1);
        if (ps < 64) bufiW[(2 * pp + 1) * 64 + ps] = m;
      }
    }
  }

  // ---- pass 3: f64 re-rank via readlane rank-count, j-major ----
  int c[4], si[4], rank[4];
  double dd[4];
  int cmax = 0;
  #pragma unroll
  for (int r = 0; r < 4; ++r) {
    c[r] = __builtin_amdgcn_readfirstlane(cnt[wv][r]);
    if (c[r] > 64) c[r] = 64;
    cmax = (c[r] > cmax) ? c[r] : cmax;
    rank[r] = 0;
  }
  #pragma unroll
  for (int r = 0; r < 4; ++r) {
    int nq = n0 + r;
    float qxf = pts3[3 * nq], qyf = pts3[3 * nq + 1], qzf = pts3[3 * nq + 2];
    if (lane < c[r]) {
      si[r] = bufiW[r * 64 + lane];
      float px = pts3[3 * si[r]], py = pts3[3 * si[r] + 1], pz = pts3[3 * si[r] + 2];
      double dqx = (double)qxf, dqy = (double)qyf, dqz = (double)qzf;
      double dpx = (double)px, dpy = (double)py, dpz = (double)pz;
      double dot = dqx * dpx + dqy * dpy + dqz * dpz;
      double sqn = dqx * dqx + dqy * dqy + dqz * dqz;
      double sqm = dpx * dpx + dpy * dpy + dpz * dpz;
      dd[r] = (sqn - 2.0 * dot) + sqm;             // self -> exactly 0.0
    } else { dd[r] = (double)INFINITY; si[r] = 0x7FFFFFFF; }
  }
  #pragma unroll 1
  for (int j = 0; j < cmax; ++j) {
    #pragma unroll
    for (int r = 0; r < 4; ++r) {
      int jlo = __builtin_amdgcn_readlane(__double2loint(dd[r]), j);
      int jhi = __builtin_amdgcn_readlane(__double2hiint(dd[r]), j);
      int ji  = __builtin_amdgcn_readlane(si[r], j);
      double jd = __hiloint2double(jhi, jlo);
      if (jd < dd[r] || (jd == dd[r] && ji < si[r])) ++rank[r];
    }
  }
  #pragma unroll
  for (int r = 0; r < 4; ++r)
    if (lane < c[r] && rank[r] < NSMP)
      nbrL[wv][r][rank[r]] = si[r];

  // ---- epilogue: acc then per-wave transpose slice (bufiW is dead now) ----
  #pragma unroll 1
  for (int r = 0; r < 4; ++r) {
    float a = bl[lane];
    #pragma unroll
    for (int s = 0; s < NSMP; ++s) {
      int id = nbrL[wv][r][s];          // uniform -> broadcast ds_read
      float px = pts3[3 * id], py = pts3[3 * id + 1], pz = pts3[3 * id + 2];
      a = fmaf(wl[(s * 3 + 0) * 64 + lane], px, a);
      a = fmaf(wl[(s * 3 + 1) * 64 + lane], py, a);
      a = fmaf(wl[(s * 3 + 2) * 64 + lane], pz, a);
    }
    transF[r * 65 + lane] = a;          // padded row -> conflict-free
  }
  __syncthreads();

  // coalesced store: thread (p = tid>>4, t16 = tid&15) writes n = nb + 4*t16 .. +3
  {
    int p = tid >> 4, t16 = tid & 15;
    float4 v;
    v.x = trans[t16 * 260 + 0 * 65 + p];
    v.y = trans[t16 * 260 + 1 * 65 + p];
    v.z = trans[t16 * 260 + 2 * 65 + p];
    v.w = trans[t16 * 260 + 3 * 65 + p];
    *(float4*)(out + ((size_t)b * 64 + p) * NPTS + nb + 4 * t16) = v;
  }
}

extern "C" void kernel_launch(void* const* d_in, const int* in_sizes, int n_in,
                              void* d_out, int out_size, void* d_ws, size_t ws_size,
                              hipStream_t stream) {
  (void)in_sizes; (void)n_in; (void)out_size; (void)ws_size;
  const float* pos = (const float*)d_in[0];
  const float* w1  = (const float*)d_in[1];
  const float* b1  = (const float*)d_in[2];
  const float* w2  = (const float*)d_in[3];
  const float* b2  = (const float*)d_in[4];
  float* out = (float*)d_out;

  // workspace: Wn (30*64 f32) then bb (64 f32)
  float* wn = (float*)d_ws;
  float* bb = (float*)((char*)d_ws + 30 * 64 * 4);

  prep_kernel<<<dim3(1), dim3(256), 0, stream>>>(w1, b1, w2, b2, wn, bb);
  topk_kernel<<<dim3(64, 8), dim3(1024), 0, stream>>>(pos, wn, bb, out);
}